// Round 2
// baseline (330.358 us; speedup 1.0000x reference)
//
#include <hip/hip_runtime.h>
#include <stdint.h>

// StandardAttention: B=16, N=1024, DIM=768, H=12, Dh=64, SCALE=0.125
// cvt(x,w_qkv,w_proj) -> gemm_qkv (256^2 tile, 8-wave, deep-prefetch counted-vmcnt)
// -> flash_attn (S^T form, 2^x, no online max; l via MFMA-ones)
// -> gemm_proj (proven 128^2 m97-structure, 3 blocks/CU TLP).

typedef unsigned short u16;
typedef __attribute__((ext_vector_type(8))) short s16x8;   // 8 x bf16 MFMA frag
typedef __attribute__((ext_vector_type(4))) float f32x4;   // MFMA accum
typedef __attribute__((ext_vector_type(4))) unsigned short u16x4;

#define SEQ 1024
#define NHEAD 12
#define HD 64

__device__ __forceinline__ u16 f2bf(float f) {
  union { float f; uint32_t u; } v; v.f = f;
  uint32_t u = v.u;
  return (u16)((u + 0x7FFFu + ((u >> 16) & 1u)) >> 16);   // RNE
}

__device__ __forceinline__ float exp2_fast(float x) {
  return __builtin_amdgcn_exp2f(x);
}

__device__ __forceinline__ uint32_t pk_bf16(float a, float b) {
#if __has_builtin(__builtin_amdgcn_cvt_pk_bf16_f32)
  typedef __attribute__((ext_vector_type(2))) __bf16 bf2;
  union { bf2 v; uint32_t u; } c;
  c.v = __builtin_amdgcn_cvt_pk_bf16_f32(a, b);
  return c.u;
#else
  union { float f; uint32_t u; } ua, ub; ua.f = a; ub.f = b;
  const uint32_t ra = ua.u + 0x8000u, rb = ub.u + 0x8000u;
  return __builtin_amdgcn_perm(ra, rb, 0x03020706u);
#endif
}

__device__ __forceinline__ void gld_lds16(const void* g, void* l) {
  __builtin_amdgcn_global_load_lds((const __attribute__((address_space(1))) void*)g,
                                   (__attribute__((address_space(3))) void*)l, 16, 0, 0);
}

// barrier WITHOUT the __syncthreads vmcnt(0) drain; compiler fence + sched pin.
__device__ __forceinline__ void phase_bar() {
  __builtin_amdgcn_sched_barrier(0);
  asm volatile("" ::: "memory");
  __builtin_amdgcn_s_barrier();
  asm volatile("" ::: "memory");
  __builtin_amdgcn_sched_barrier(0);
}

__global__ void cvt_bf16(const float* __restrict__ in, u16* __restrict__ out, int n4) {
  int i = blockIdx.x * blockDim.x + threadIdx.x;
  if (i < n4) {
    float4 f = ((const float4*)in)[i];
    u16x4 o;
    o.x = f2bf(f.x); o.y = f2bf(f.y); o.z = f2bf(f.z); o.w = f2bf(f.w);
    ((u16x4*)out)[i] = o;
  }
}

// QKV: C = A[16384,768] @ B^T, B row-major [2304,768]. 256x256 tile, BK=64,
// 8 waves (2Mx4N). 4 phases/K-tile (one mi-quadrant each, 16 MFMA).
// Deep-prefetch ledger: ALL 8 loads of tile t+1 issued in phase 1 (after its
// reads); single vmcnt(0) at end of phase 3 retires loads ~2.3 phases old.
// At every phase-1 read point, outstanding VMEM = 0 (robust to compiler waits).
// Scatter epilogue: q(*0.125*log2e)/k to [B,H,N,64], V TRANSPOSED to [B,H,64,N].
__global__ __launch_bounds__(512, 2)
void gemm_qkv(const u16* __restrict__ A, const u16* __restrict__ B,
              u16* __restrict__ q, u16* __restrict__ k, u16* __restrict__ v) {
  __shared__ u16 As[2][256 * 64];
  __shared__ u16 Bs[2][256 * 64];
  constexpr int NTN = 9;                      // 2304/256
  constexpr int NWG = 64 * NTN;               // 576 (%8 == 0)
  constexpr int CPX = NWG / 8;

  const int tid = threadIdx.x;
  const int wv = tid >> 6, lane = tid & 63;
  const int quad = lane >> 4, l16 = lane & 15;
  const int bid = blockIdx.x;
  const int swz = (bid & 7) * CPX + (bid >> 3);   // bijective XCD swizzle
  const int m0 = (swz / NTN) * 256;               // intra-XCD neighbors share A panel
  const int n0 = (swz % NTN) * 256;
  const int wm = (wv >> 2) * 128, wn = (wv & 3) * 64;
  const int srow = tid >> 3, slot = tid & 7;

// stage one 128x64 half of one matrix (2 x 16B/thread); chunk slot = slot ^ (row&7)
#define STAGE_H(MAT, GPTR, g0, bufi, kt, half)                               \
  do {                                                                       \
    _Pragma("unroll")                                                        \
    for (int j = 0; j < 2; j++) {                                            \
      const int row_ = (half) * 128 + j * 64 + srow;                         \
      const int c_ = slot ^ (row_ & 7);                                      \
      gld_lds16(GPTR + (size_t)((g0) + row_) * 768 + (kt) + c_ * 8,          \
                &MAT[bufi][((half) * 128 + j * 64 + wv * 8) * 64]);          \
    }                                                                        \
  } while (0)

#define STAGE_ALL(bufi, kt)                                                  \
  do {                                                                       \
    STAGE_H(As, A, m0, bufi, kt, 0);                                         \
    STAGE_H(As, A, m0, bufi, kt, 1);                                         \
    STAGE_H(Bs, B, n0, bufi, kt, 0);                                         \
    STAGE_H(Bs, B, n0, bufi, kt, 1);                                         \
  } while (0)

#define READ_A(qd)                                                           \
  do {                                                                       \
    _Pragma("unroll")                                                        \
    for (int i = 0; i < 2; i++) {                                            \
      const int ra_ = wm + ((qd) * 2 + i) * 16 + l16;                        \
      _Pragma("unroll")                                                      \
      for (int ks = 0; ks < 2; ks++)                                         \
        af[i][ks] = *(const s16x8*)&As[buf][ra_ * 64 + (((ks * 4 + quad) ^ (ra_ & 7)) * 8)]; \
    }                                                                        \
  } while (0)

#define READ_B()                                                             \
  do {                                                                       \
    _Pragma("unroll")                                                        \
    for (int ni = 0; ni < 4; ni++) {                                         \
      const int rb_ = wn + ni * 16 + l16;                                    \
      _Pragma("unroll")                                                      \
      for (int ks = 0; ks < 2; ks++)                                         \
        bf[ks][ni] = *(const s16x8*)&Bs[buf][rb_ * 64 + (((ks * 4 + quad) ^ (rb_ & 7)) * 8)]; \
    }                                                                        \
  } while (0)

#define MFMA_Q(qd)                                                           \
  do {                                                                       \
    __builtin_amdgcn_s_setprio(1);                                           \
    _Pragma("unroll")                                                        \
    for (int i = 0; i < 2; i++)                                              \
      _Pragma("unroll")                                                      \
      for (int ni = 0; ni < 4; ni++) {                                       \
        acc[(qd) * 2 + i][ni] = __builtin_amdgcn_mfma_f32_16x16x32_bf16(     \
            af[i][0], bf[0][ni], acc[(qd) * 2 + i][ni], 0, 0, 0);            \
        acc[(qd) * 2 + i][ni] = __builtin_amdgcn_mfma_f32_16x16x32_bf16(     \
            af[i][1], bf[1][ni], acc[(qd) * 2 + i][ni], 0, 0, 0);            \
      }                                                                      \
    __builtin_amdgcn_s_setprio(0);                                           \
  } while (0)

  f32x4 acc[8][4];
#pragma unroll
  for (int i = 0; i < 8; i++)
#pragma unroll
    for (int j = 0; j < 4; j++) { acc[i][j].x = 0.f; acc[i][j].y = 0.f; acc[i][j].z = 0.f; acc[i][j].w = 0.f; }

  // Prologue: tile 0 complete, drained.
  STAGE_ALL(0, 0);
  asm volatile("s_waitcnt vmcnt(0)" ::: "memory");
  phase_bar();

  for (int t = 0; t < 12; t++) {
    const int buf = t & 1;
    s16x8 af[2][2], bf[2][4];

    // ---- phase 1: reads first (outstanding VMEM == 0 here), then prefetch
    //      ALL of tile t+1 (8 gld_lds16) into buf^1.
    READ_B();
    READ_A(0);
    if (t < 11) STAGE_ALL(buf ^ 1, (t + 1) * 64);
    phase_bar();
    MFMA_Q(0);
    phase_bar();

    // ---- phase 2
    READ_A(1);
    phase_bar();
    MFMA_Q(1);
    phase_bar();

    // ---- phase 3: counted drain — loads are ~2.3 phases old here.
    READ_A(2);
    phase_bar();
    MFMA_Q(2);
    asm volatile("s_waitcnt vmcnt(0)" ::: "memory");
    phase_bar();

    // ---- phase 4
    READ_A(3);
    phase_bar();
    MFMA_Q(3);
    phase_bar();
  }

#pragma unroll
  for (int ni = 0; ni < 4; ni++) {
    const int n = n0 + wn + ni * 16 + l16;
    const int which = n / 768;          // constant per ni-block
    const int rc = n % 768;
    const int head = rc >> 6, d = rc & 63;
#pragma unroll
    for (int mi = 0; mi < 8; mi++) {
#pragma unroll
      for (int r = 0; r < 4; r++) {
        const int m = m0 + wm + mi * 16 + quad * 4 + r;
        const int b = m >> 10, rr = m & 1023;
        const float val = acc[mi][ni][r];
        if (which == 0)   // fold SCALE * log2(e) so flash uses 2^x directly
          q[((size_t)(b * NHEAD + head) * SEQ + rr) * HD + d] = f2bf(val * 0.18033688011112042f);
        else if (which == 1)
          k[((size_t)(b * NHEAD + head) * SEQ + rr) * HD + d] = f2bf(val);
        else
          v[((size_t)(b * NHEAD + head) * HD + d) * SEQ + rr] = f2bf(val);
      }
    }
  }
#undef STAGE_H
#undef STAGE_ALL
#undef READ_A
#undef READ_B
#undef MFMA_Q
}

// Proj: proven 128^2 m97-structure, 3 blocks/CU. C = A[16384,768] @ B^T + bias, fp32.
__global__ __launch_bounds__(256, 3)
void gemm_proj(const u16* __restrict__ A, const u16* __restrict__ B,
               float* __restrict__ out, const float* __restrict__ bias) {
  __shared__ u16 As[128 * 64];
  __shared__ u16 Bs[128 * 64];
  const int tid = threadIdx.x;
  const int wv = tid >> 6, lane = tid & 63;
  const int quad = lane >> 4, l16 = lane & 15;
  const int m0 = blockIdx.x * 128, n0 = blockIdx.y * 128;
  const int wm = (wv & 1) * 64, wn = (wv >> 1) * 64;

  f32x4 acc[4][4];
#pragma unroll
  for (int i = 0; i < 4; i++)
#pragma unroll
    for (int j = 0; j < 4; j++) { acc[i][j].x = 0.f; acc[i][j].y = 0.f; acc[i][j].z = 0.f; acc[i][j].w = 0.f; }

  const int srow = (lane >> 3);
  const int scp = lane & 7;

  for (int kt = 0; kt < 768; kt += 64) {
    __syncthreads();
#pragma unroll
    for (int i = 0; i < 4; i++) {
      const int t = wv * 4 + i;
      const int row = t * 8 + srow;
      const int c = scp ^ (row & 7);
      gld_lds16(A + (size_t)(m0 + row) * 768 + kt + c * 8, &As[t * 512]);
      gld_lds16(B + (size_t)(n0 + row) * 768 + kt + c * 8, &Bs[t * 512]);
    }
    __syncthreads();
#pragma unroll
    for (int ks = 0; ks < 2; ks++) {
      s16x8 af[4], bf[4];
#pragma unroll
      for (int mi = 0; mi < 4; mi++) {
        const int ra = wm + mi * 16 + l16;
        const int ca = ((ks * 4 + quad) ^ (ra & 7)) * 8;
        af[mi] = *(const s16x8*)&As[ra * 64 + ca];
        const int rb = wn + mi * 16 + l16;
        const int cb = ((ks * 4 + quad) ^ (rb & 7)) * 8;
        bf[mi] = *(const s16x8*)&Bs[rb * 64 + cb];
      }
#pragma unroll
      for (int mi = 0; mi < 4; mi++)
#pragma unroll
        for (int ni = 0; ni < 4; ni++)
          acc[mi][ni] = __builtin_amdgcn_mfma_f32_16x16x32_bf16(af[mi], bf[ni], acc[mi][ni], 0, 0, 0);
    }
  }

#pragma unroll
  for (int mi = 0; mi < 4; mi++)
#pragma unroll
    for (int ni = 0; ni < 4; ni++)
#pragma unroll
      for (int r = 0; r < 4; r++) {
        const int m = m0 + wm + mi * 16 + quad * 4 + r;
        const int n = n0 + wn + ni * 16 + l16;
        out[(size_t)m * 768 + n] = acc[mi][ni][r] + bias[n];
      }
}

// Flash attention, S^T form, no online max, 2^x, double-buffered K/V staging.
// l computed as P @ ones via MFMA (acc_l lands in same C-layout rows as acc).
__global__ __launch_bounds__(256, 3)
void flash_attn(const u16* __restrict__ Q, const u16* __restrict__ K,
                const u16* __restrict__ VT, u16* __restrict__ O) {
  __shared__ u16 Ks[2][64 * 64];        // [key][d], chunks swizzled by key&7
  __shared__ u16 Vs[2][64 * 64];        // [d][key], chunks swizzled by d&7
  __shared__ u16 Ps[4][32 * 64];        // per-wave [qrow][key]

  const int tid = threadIdx.x;
  const int wv = tid >> 6, lane = tid & 63;
  const int quad = lane >> 4, l16 = lane & 15;
  const int bh = blockIdx.x;
  const int q0 = blockIdx.y * 128 + wv * 32;
  const size_t base = (size_t)bh * SEQ * HD;
  const size_t vbase = (size_t)bh * HD * SEQ;
  u16* pw = Ps[wv];

  const int sr0 = tid >> 3;
  const int sc0 = (tid & 7) ^ (sr0 & 7);
  const int sr1 = 32 + sr0;
  const int sc1 = (tid & 7) ^ (sr1 & 7);

  s16x8 qf[2][2];
#pragma unroll
  for (int g = 0; g < 2; g++)
#pragma unroll
    for (int ks = 0; ks < 2; ks++)
      qf[g][ks] = *(const s16x8*)(Q + base + (size_t)(q0 + g * 16 + l16) * HD + ks * 32 + quad * 8);

  const s16x8 ones = {0x3F80, 0x3F80, 0x3F80, 0x3F80, 0x3F80, 0x3F80, 0x3F80, 0x3F80};

  f32x4 acc[2][4], acc_l[2];
#pragma unroll
  for (int g = 0; g < 2; g++) {
    acc_l[g].x = 0.f; acc_l[g].y = 0.f; acc_l[g].z = 0.f; acc_l[g].w = 0.f;
#pragma unroll
    for (int t = 0; t < 4; t++) { acc[g][t].x = 0.f; acc[g][t].y = 0.f; acc[g][t].z = 0.f; acc[g][t].w = 0.f; }
  }

  const int swz = l16 & 7;

  gld_lds16(K + base + (size_t)sr0 * HD + sc0 * 8, &Ks[0][wv * 512]);
  gld_lds16(VT + vbase + (size_t)sr0 * SEQ + sc0 * 8, &Vs[0][wv * 512]);
  gld_lds16(K + base + (size_t)sr1 * HD + sc1 * 8, &Ks[0][2048 + wv * 512]);
  gld_lds16(VT + vbase + (size_t)sr1 * SEQ + sc1 * 8, &Vs[0][2048 + wv * 512]);

  for (int it = 0; it < 16; it++) {
    __syncthreads();
    if (it + 1 < 16) {
      const int n1 = (it + 1) * 64;
      const int nb = (it + 1) & 1;
      gld_lds16(K + base + (size_t)(n1 + sr0) * HD + sc0 * 8, &Ks[nb][wv * 512]);
      gld_lds16(VT + vbase + (size_t)sr0 * SEQ + n1 + sc0 * 8, &Vs[nb][wv * 512]);
      gld_lds16(K + base + (size_t)(n1 + sr1) * HD + sc1 * 8, &Ks[nb][2048 + wv * 512]);
      gld_lds16(VT + vbase + (size_t)sr1 * SEQ + n1 + sc1 * 8, &Vs[nb][2048 + wv * 512]);
    }
    const u16* __restrict__ ks = Ks[it & 1];
    const u16* __restrict__ vs = Vs[it & 1];

    // S^T = K Q^T (q pre-scaled by 0.125*log2e)
    f32x4 s0[4], s1[4];
#pragma unroll
    for (int t = 0; t < 4; t++) {
      s0[t].x = 0.f; s0[t].y = 0.f; s0[t].z = 0.f; s0[t].w = 0.f;
      s1[t].x = 0.f; s1[t].y = 0.f; s1[t].z = 0.f; s1[t].w = 0.f;
      const u16* kr = &ks[(t * 16 + l16) * 64];
      const s16x8 kf0 = *(const s16x8*)&kr[(quad ^ swz) * 8];
      const s16x8 kf1 = *(const s16x8*)&kr[((4 + quad) ^ swz) * 8];
      s0[t] = __builtin_amdgcn_mfma_f32_16x16x32_bf16(kf0, qf[0][0], s0[t], 0, 0, 0);
      s0[t] = __builtin_amdgcn_mfma_f32_16x16x32_bf16(kf1, qf[0][1], s0[t], 0, 0, 0);
      s1[t] = __builtin_amdgcn_mfma_f32_16x16x32_bf16(kf0, qf[1][0], s1[t], 0, 0, 0);
      s1[t] = __builtin_amdgcn_mfma_f32_16x16x32_bf16(kf1, qf[1][1], s1[t], 0, 0, 0);
    }

    // p = 2^s
#pragma unroll
    for (int t = 0; t < 4; t++)
#pragma unroll
      for (int r = 0; r < 4; r++) {
        s0[t][r] = exp2_fast(s0[t][r]);
        s1[t][r] = exp2_fast(s1[t][r]);
      }

    // P -> per-wave LDS, packed b64, chunk-swizzled
#pragma unroll
    for (int t = 0; t < 4; t++) {
      const int p = (2 * t + (quad >> 1)) ^ swz;
      *(uint2*)&pw[l16 * 64 + p * 8 + (quad & 1) * 4] =
          make_uint2(pk_bf16(s0[t][0], s0[t][1]), pk_bf16(s0[t][2], s0[t][3]));
      *(uint2*)&pw[(16 + l16) * 64 + p * 8 + (quad & 1) * 4] =
          make_uint2(pk_bf16(s1[t][0], s1[t][1]), pk_bf16(s1[t][2], s1[t][3]));
    }

    // O += P V ; l += P @ ones (matrix pipe does the row sums)
#pragma unroll
    for (int ks2 = 0; ks2 < 2; ks2++) {
      const int cp = ((ks2 * 4 + quad) ^ swz) * 8;
      const s16x8 pf0 = *(const s16x8*)&pw[l16 * 64 + cp];
      const s16x8 pf1 = *(const s16x8*)&pw[(16 + l16) * 64 + cp];
      acc_l[0] = __builtin_amdgcn_mfma_f32_16x16x32_bf16(pf0, ones, acc_l[0], 0, 0, 0);
      acc_l[1] = __builtin_amdgcn_mfma_f32_16x16x32_bf16(pf1, ones, acc_l[1], 0, 0, 0);
#pragma unroll
      for (int t2 = 0; t2 < 4; t2++) {
        const s16x8 vf = *(const s16x8*)&vs[(t2 * 16 + l16) * 64 + cp];
        acc[0][t2] = __builtin_amdgcn_mfma_f32_16x16x32_bf16(pf0, vf, acc[0][t2], 0, 0, 0);
        acc[1][t2] = __builtin_amdgcn_mfma_f32_16x16x32_bf16(pf1, vf, acc[1][t2], 0, 0, 0);
      }
    }
  }

  // write attn_out bf16 [B, N, H*64]; acc_l rows coincide with acc rows
  const int b = bh / NHEAD, h = bh % NHEAD;
#pragma unroll
  for (int g = 0; g < 2; g++) {
#pragma unroll
    for (int r = 0; r < 4; r++) {
      const float li = 1.0f / acc_l[g][r];
      const int qrow = q0 + g * 16 + quad * 4 + r;
      u16* op = O + (size_t)(b * SEQ + qrow) * 768 + h * HD;
#pragma unroll
      for (int t2 = 0; t2 < 4; t2++)
        op[t2 * 16 + l16] = f2bf(acc[g][t2][r] * li);
    }
  }
}

extern "C" void kernel_launch(void* const* d_in, const int* in_sizes, int n_in,
                              void* d_out, int out_size, void* d_ws, size_t ws_size,
                              hipStream_t stream) {
  (void)in_sizes; (void)n_in; (void)out_size; (void)ws_size;
  const float* x      = (const float*)d_in[0];
  const float* w_qkv  = (const float*)d_in[1];
  const float* w_proj = (const float*)d_in[2];
  const float* b_proj = (const float*)d_in[3];

  const size_t SZ_X   = (size_t)16384 * 768;
  const size_t SZ_WQ  = (size_t)2304 * 768;
  const size_t SZ_WP  = (size_t)768 * 768;
  const size_t SZ_HED = (size_t)16 * NHEAD * SEQ * HD;

  u16* xb   = (u16*)d_ws;
  u16* wqb  = xb + SZ_X;
  u16* wpb  = wqb + SZ_WQ;
  u16* qb   = wpb + SZ_WP;
  u16* kb   = qb + SZ_HED;
  u16* vtb  = kb + SZ_HED;     // V transposed [bh][d][n]
  u16* attn = vtb + SZ_HED;

  cvt_bf16<<<(int)(SZ_X / 4 / 256), 256, 0, stream>>>(x, xb, (int)(SZ_X / 4));
  cvt_bf16<<<(int)(SZ_WQ / 4 / 256), 256, 0, stream>>>(w_qkv, wqb, (int)(SZ_WQ / 4));
  cvt_bf16<<<(int)(SZ_WP / 4 / 256), 256, 0, stream>>>(w_proj, wpb, (int)(SZ_WP / 4));

  gemm_qkv<<<dim3(576), 512, 0, stream>>>(xb, wqb, qb, kb, vtb);
  flash_attn<<<dim3(192, 8), 256, 0, stream>>>(qb, kb, vtb, attn);
  gemm_proj<<<dim3(128, 6), 256, 0, stream>>>(attn, wpb, (float*)d_out, b_proj);
}

// Round 3
// 282.011 us; speedup vs baseline: 1.1714x; 1.1714x over previous
//
#include <hip/hip_runtime.h>
#include <stdint.h>

// StandardAttention: B=16, N=1024, DIM=768, H=12, Dh=64, SCALE=0.125
// fused cvt(x,w_qkv,w_proj) -> gemm_qkv (proven 128^2 m97-structure, 3 blocks/CU)
// -> flash_attn (S^T form, 2^x, no online max; l via MFMA-ones; T5 setprio)
// -> gemm_proj (same 128^2 structure, +bias fp32).
// NOTE: 256^2 8-phase rewrite tried (r1/r2): 137us vs 87us here. At K=768 (12
// K-tiles) and 1 block/CU, grid quantization (576 blks = 3 serialized passes)
// + 2-wave/SIMD lockstep lose to 3-block/CU TLP. Do not revisit without
// changing block count to a multiple of 256 AND >2 waves/SIMD independence.

typedef unsigned short u16;
typedef __attribute__((ext_vector_type(8))) short s16x8;   // 8 x bf16 MFMA frag
typedef __attribute__((ext_vector_type(4))) float f32x4;   // MFMA accum
typedef __attribute__((ext_vector_type(4))) unsigned short u16x4;

#define SEQ 1024
#define NHEAD 12
#define HD 64

__device__ __forceinline__ u16 f2bf(float f) {
  union { float f; uint32_t u; } v; v.f = f;
  uint32_t u = v.u;
  return (u16)((u + 0x7FFFu + ((u >> 16) & 1u)) >> 16);   // RNE
}

__device__ __forceinline__ float exp2_fast(float x) {
  return __builtin_amdgcn_exp2f(x);
}

__device__ __forceinline__ uint32_t pk_bf16(float a, float b) {
#if __has_builtin(__builtin_amdgcn_cvt_pk_bf16_f32)
  typedef __attribute__((ext_vector_type(2))) __bf16 bf2;
  union { bf2 v; uint32_t u; } c;
  c.v = __builtin_amdgcn_cvt_pk_bf16_f32(a, b);
  return c.u;
#else
  union { float f; uint32_t u; } ua, ub; ua.f = a; ub.f = b;
  const uint32_t ra = ua.u + 0x8000u, rb = ub.u + 0x8000u;
  return __builtin_amdgcn_perm(ra, rb, 0x03020706u);
#endif
}

__device__ __forceinline__ void gld_lds16(const void* g, void* l) {
  __builtin_amdgcn_global_load_lds((const __attribute__((address_space(1))) void*)g,
                                   (__attribute__((address_space(3))) void*)l, 16, 0, 0);
}

// One launch converts x, w_qkv, w_proj (3 disjoint fp32 sources -> contiguous
// bf16 workspace regions). Block-range select; branches are wave-uniform
// except at the two boundaries.
__global__ void cvt_bf16_3(const float* __restrict__ in0, u16* __restrict__ out0, int n0,
                           const float* __restrict__ in1, u16* __restrict__ out1, int n1,
                           const float* __restrict__ in2, u16* __restrict__ out2, int n2) {
  int i = blockIdx.x * blockDim.x + threadIdx.x;
  const float* in; u16* out;
  if (i < n0)            { in = in0; out = out0; }
  else if (i < n0 + n1)  { in = in1; out = out1; i -= n0; }
  else if (i < n0 + n1 + n2) { in = in2; out = out2; i -= n0 + n1; }
  else return;
  float4 f = ((const float4*)in)[i];
  u16x4 o;
  o.x = f2bf(f.x); o.y = f2bf(f.y); o.z = f2bf(f.z); o.w = f2bf(f.w);
  ((u16x4*)out)[i] = o;
}

// C = A[M,768] @ B^T, B row-major [N,768]. 128x128 tile, BK=64, 3 blocks/CU.
// EPI=0: scatter q(*0.125*log2e)/k to [B,H,N,64], V TRANSPOSED to [B,H,64,N].
// EPI=1: +bias, fp32 out.
template <int EPI>
__global__ __launch_bounds__(256, 3)
void gemm_bt(const u16* __restrict__ A, const u16* __restrict__ B,
             u16* __restrict__ q, u16* __restrict__ k, u16* __restrict__ v,
             float* __restrict__ out, const float* __restrict__ bias) {
  __shared__ u16 As[128 * 64];
  __shared__ u16 Bs[128 * 64];
  const int tid = threadIdx.x;
  const int wv = tid >> 6, lane = tid & 63;
  const int quad = lane >> 4, l16 = lane & 15;
  const int m0 = blockIdx.x * 128, n0 = blockIdx.y * 128;
  const int wm = (wv & 1) * 64, wn = (wv >> 1) * 64;

  f32x4 acc[4][4];
#pragma unroll
  for (int i = 0; i < 4; i++)
#pragma unroll
    for (int j = 0; j < 4; j++) { acc[i][j].x = 0.f; acc[i][j].y = 0.f; acc[i][j].z = 0.f; acc[i][j].w = 0.f; }

  const int srow = (lane >> 3);
  const int scp = lane & 7;

  for (int kt = 0; kt < 768; kt += 64) {
    __syncthreads();
#pragma unroll
    for (int i = 0; i < 4; i++) {
      const int t = wv * 4 + i;
      const int row = t * 8 + srow;
      const int c = scp ^ (row & 7);
      gld_lds16(A + (size_t)(m0 + row) * 768 + kt + c * 8, &As[t * 512]);
      gld_lds16(B + (size_t)(n0 + row) * 768 + kt + c * 8, &Bs[t * 512]);
    }
    __syncthreads();
#pragma unroll
    for (int ks = 0; ks < 2; ks++) {
      s16x8 af[4], bf[4];
#pragma unroll
      for (int mi = 0; mi < 4; mi++) {
        const int ra = wm + mi * 16 + l16;
        const int ca = ((ks * 4 + quad) ^ (ra & 7)) * 8;
        af[mi] = *(const s16x8*)&As[ra * 64 + ca];
        const int rb = wn + mi * 16 + l16;
        const int cb = ((ks * 4 + quad) ^ (rb & 7)) * 8;
        bf[mi] = *(const s16x8*)&Bs[rb * 64 + cb];
      }
#pragma unroll
      for (int mi = 0; mi < 4; mi++)
#pragma unroll
        for (int ni = 0; ni < 4; ni++)
          acc[mi][ni] = __builtin_amdgcn_mfma_f32_16x16x32_bf16(af[mi], bf[ni], acc[mi][ni], 0, 0, 0);
    }
  }

#pragma unroll
  for (int mi = 0; mi < 4; mi++) {
#pragma unroll
    for (int ni = 0; ni < 4; ni++) {
#pragma unroll
      for (int r = 0; r < 4; r++) {
        const int m = m0 + wm + mi * 16 + quad * 4 + r;
        const int n = n0 + wn + ni * 16 + l16;
        const float val = acc[mi][ni][r];
        if (EPI == 0) {
          const int which = n / 768;
          const int rc = n % 768;
          const int head = rc >> 6, d = rc & 63;
          const int b = m >> 10, rr = m & 1023;
          if (which == 0)   // fold SCALE * log2(e) so flash uses 2^x directly
            q[((size_t)(b * NHEAD + head) * SEQ + rr) * HD + d] = f2bf(val * 0.18033688011112042f);
          else if (which == 1)
            k[((size_t)(b * NHEAD + head) * SEQ + rr) * HD + d] = f2bf(val);
          else
            v[((size_t)(b * NHEAD + head) * HD + d) * SEQ + rr] = f2bf(val);
        } else {
          out[(size_t)m * 768 + n] = val + bias[n];
        }
      }
    }
  }
}

// Flash attention, S^T form, no online max, 2^x, double-buffered K/V staging.
// l computed as P @ ones via MFMA (acc_l lands in same C-layout rows as acc).
// T5: setprio(1) around MFMA clusters (3 independent blocks/CU -> scheduler
// has waves at different phases to arbitrate; +4-7% in m191's attn A/B).
__global__ __launch_bounds__(256, 3)
void flash_attn(const u16* __restrict__ Q, const u16* __restrict__ K,
                const u16* __restrict__ VT, u16* __restrict__ O) {
  __shared__ u16 Ks[2][64 * 64];        // [key][d], chunks swizzled by key&7
  __shared__ u16 Vs[2][64 * 64];        // [d][key], chunks swizzled by d&7
  __shared__ u16 Ps[4][32 * 64];        // per-wave [qrow][key]

  const int tid = threadIdx.x;
  const int wv = tid >> 6, lane = tid & 63;
  const int quad = lane >> 4, l16 = lane & 15;
  const int bh = blockIdx.x;
  const int q0 = blockIdx.y * 128 + wv * 32;
  const size_t base = (size_t)bh * SEQ * HD;
  const size_t vbase = (size_t)bh * HD * SEQ;
  u16* pw = Ps[wv];

  const int sr0 = tid >> 3;
  const int sc0 = (tid & 7) ^ (sr0 & 7);
  const int sr1 = 32 + sr0;
  const int sc1 = (tid & 7) ^ (sr1 & 7);

  s16x8 qf[2][2];
#pragma unroll
  for (int g = 0; g < 2; g++)
#pragma unroll
    for (int ks = 0; ks < 2; ks++)
      qf[g][ks] = *(const s16x8*)(Q + base + (size_t)(q0 + g * 16 + l16) * HD + ks * 32 + quad * 8);

  const s16x8 ones = {0x3F80, 0x3F80, 0x3F80, 0x3F80, 0x3F80, 0x3F80, 0x3F80, 0x3F80};

  f32x4 acc[2][4], acc_l[2];
#pragma unroll
  for (int g = 0; g < 2; g++) {
    acc_l[g].x = 0.f; acc_l[g].y = 0.f; acc_l[g].z = 0.f; acc_l[g].w = 0.f;
#pragma unroll
    for (int t = 0; t < 4; t++) { acc[g][t].x = 0.f; acc[g][t].y = 0.f; acc[g][t].z = 0.f; acc[g][t].w = 0.f; }
  }

  const int swz = l16 & 7;

  gld_lds16(K + base + (size_t)sr0 * HD + sc0 * 8, &Ks[0][wv * 512]);
  gld_lds16(VT + vbase + (size_t)sr0 * SEQ + sc0 * 8, &Vs[0][wv * 512]);
  gld_lds16(K + base + (size_t)sr1 * HD + sc1 * 8, &Ks[0][2048 + wv * 512]);
  gld_lds16(VT + vbase + (size_t)sr1 * SEQ + sc1 * 8, &Vs[0][2048 + wv * 512]);

  for (int it = 0; it < 16; it++) {
    __syncthreads();
    if (it + 1 < 16) {
      const int n1 = (it + 1) * 64;
      const int nb = (it + 1) & 1;
      gld_lds16(K + base + (size_t)(n1 + sr0) * HD + sc0 * 8, &Ks[nb][wv * 512]);
      gld_lds16(VT + vbase + (size_t)sr0 * SEQ + n1 + sc0 * 8, &Vs[nb][wv * 512]);
      gld_lds16(K + base + (size_t)(n1 + sr1) * HD + sc1 * 8, &Ks[nb][2048 + wv * 512]);
      gld_lds16(VT + vbase + (size_t)sr1 * SEQ + n1 + sc1 * 8, &Vs[nb][2048 + wv * 512]);
    }
    const u16* __restrict__ ks = Ks[it & 1];
    const u16* __restrict__ vs = Vs[it & 1];

    // S^T = K Q^T (q pre-scaled by 0.125*log2e)
    f32x4 s0[4], s1[4];
    __builtin_amdgcn_s_setprio(1);
#pragma unroll
    for (int t = 0; t < 4; t++) {
      s0[t].x = 0.f; s0[t].y = 0.f; s0[t].z = 0.f; s0[t].w = 0.f;
      s1[t].x = 0.f; s1[t].y = 0.f; s1[t].z = 0.f; s1[t].w = 0.f;
      const u16* kr = &ks[(t * 16 + l16) * 64];
      const s16x8 kf0 = *(const s16x8*)&kr[(quad ^ swz) * 8];
      const s16x8 kf1 = *(const s16x8*)&kr[((4 + quad) ^ swz) * 8];
      s0[t] = __builtin_amdgcn_mfma_f32_16x16x32_bf16(kf0, qf[0][0], s0[t], 0, 0, 0);
      s0[t] = __builtin_amdgcn_mfma_f32_16x16x32_bf16(kf1, qf[0][1], s0[t], 0, 0, 0);
      s1[t] = __builtin_amdgcn_mfma_f32_16x16x32_bf16(kf0, qf[1][0], s1[t], 0, 0, 0);
      s1[t] = __builtin_amdgcn_mfma_f32_16x16x32_bf16(kf1, qf[1][1], s1[t], 0, 0, 0);
    }
    __builtin_amdgcn_s_setprio(0);

    // p = 2^s
#pragma unroll
    for (int t = 0; t < 4; t++)
#pragma unroll
      for (int r = 0; r < 4; r++) {
        s0[t][r] = exp2_fast(s0[t][r]);
        s1[t][r] = exp2_fast(s1[t][r]);
      }

    // P -> per-wave LDS, packed b64, chunk-swizzled
#pragma unroll
    for (int t = 0; t < 4; t++) {
      const int p = (2 * t + (quad >> 1)) ^ swz;
      *(uint2*)&pw[l16 * 64 + p * 8 + (quad & 1) * 4] =
          make_uint2(pk_bf16(s0[t][0], s0[t][1]), pk_bf16(s0[t][2], s0[t][3]));
      *(uint2*)&pw[(16 + l16) * 64 + p * 8 + (quad & 1) * 4] =
          make_uint2(pk_bf16(s1[t][0], s1[t][1]), pk_bf16(s1[t][2], s1[t][3]));
    }

    // O += P V ; l += P @ ones (matrix pipe does the row sums)
    __builtin_amdgcn_s_setprio(1);
#pragma unroll
    for (int ks2 = 0; ks2 < 2; ks2++) {
      const int cp = ((ks2 * 4 + quad) ^ swz) * 8;
      const s16x8 pf0 = *(const s16x8*)&pw[l16 * 64 + cp];
      const s16x8 pf1 = *(const s16x8*)&pw[(16 + l16) * 64 + cp];
      acc_l[0] = __builtin_amdgcn_mfma_f32_16x16x32_bf16(pf0, ones, acc_l[0], 0, 0, 0);
      acc_l[1] = __builtin_amdgcn_mfma_f32_16x16x32_bf16(pf1, ones, acc_l[1], 0, 0, 0);
#pragma unroll
      for (int t2 = 0; t2 < 4; t2++) {
        const s16x8 vf = *(const s16x8*)&vs[(t2 * 16 + l16) * 64 + cp];
        acc[0][t2] = __builtin_amdgcn_mfma_f32_16x16x32_bf16(pf0, vf, acc[0][t2], 0, 0, 0);
        acc[1][t2] = __builtin_amdgcn_mfma_f32_16x16x32_bf16(pf1, vf, acc[1][t2], 0, 0, 0);
      }
    }
    __builtin_amdgcn_s_setprio(0);
  }

  // write attn_out bf16 [B, N, H*64]; acc_l rows coincide with acc rows
  const int b = bh / NHEAD, h = bh % NHEAD;
#pragma unroll
  for (int g = 0; g < 2; g++) {
#pragma unroll
    for (int r = 0; r < 4; r++) {
      const float li = 1.0f / acc_l[g][r];
      const int qrow = q0 + g * 16 + quad * 4 + r;
      u16* op = O + (size_t)(b * SEQ + qrow) * 768 + h * HD;
#pragma unroll
      for (int t2 = 0; t2 < 4; t2++)
        op[t2 * 16 + l16] = f2bf(acc[g][t2][r] * li);
    }
  }
}

extern "C" void kernel_launch(void* const* d_in, const int* in_sizes, int n_in,
                              void* d_out, int out_size, void* d_ws, size_t ws_size,
                              hipStream_t stream) {
  (void)in_sizes; (void)n_in; (void)out_size; (void)ws_size;
  const float* x      = (const float*)d_in[0];
  const float* w_qkv  = (const float*)d_in[1];
  const float* w_proj = (const float*)d_in[2];
  const float* b_proj = (const float*)d_in[3];

  const size_t SZ_X   = (size_t)16384 * 768;
  const size_t SZ_WQ  = (size_t)2304 * 768;
  const size_t SZ_WP  = (size_t)768 * 768;
  const size_t SZ_HED = (size_t)16 * NHEAD * SEQ * HD;

  u16* xb   = (u16*)d_ws;
  u16* wqb  = xb + SZ_X;
  u16* wpb  = wqb + SZ_WQ;
  u16* qb   = wpb + SZ_WP;
  u16* kb   = qb + SZ_HED;
  u16* vtb  = kb + SZ_HED;     // V transposed [bh][d][n]
  u16* attn = vtb + SZ_HED;

  const int n0 = (int)(SZ_X / 4), n1 = (int)(SZ_WQ / 4), n2 = (int)(SZ_WP / 4);
  const int nblk = (n0 + n1 + n2 + 255) / 256;
  cvt_bf16_3<<<nblk, 256, 0, stream>>>(x, xb, n0, w_qkv, wqb, n1, w_proj, wpb, n2);

  gemm_bt<0><<<dim3(128, 18), 256, 0, stream>>>(xb, wqb, qb, kb, vtb, nullptr, nullptr);
  flash_attn<<<dim3(192, 8), 256, 0, stream>>>(qb, kb, vtb, attn);
  gemm_bt<1><<<dim3(128, 6), 256, 0, stream>>>(attn, wpb, nullptr, nullptr, nullptr,
                                               (float*)d_out, b_proj);
}

// Round 4
// 261.709 us; speedup vs baseline: 1.2623x; 1.0776x over previous
//
#include <hip/hip_runtime.h>
#include <stdint.h>

// StandardAttention: B=16, N=1024, DIM=768, H=12, Dh=64, SCALE=0.125
// fused cvt(x,w_qkv,w_proj) -> gemm_qkv (proven 128^2 m97-structure, 3 blocks/CU)
// -> flash_attn (S^T form, 2^x, no online max; l via MFMA-ones; in-register P)
// -> gemm_proj (same 128^2 structure, +bias fp32).
// NOTE r1/r2: 256^2 8-phase rewrite = 137us vs 87us here (grid quantization:
// 576 blks @ 1/CU = 3 serialized passes; 2-wave/SIMD lockstep). Don't revisit.
// NOTE r4: P never touches LDS. Key axis is a private contraction axis, so
// P-columns and V-rows are permuted identically by sigma(n) =
// ((n>>2)&3)*8 + ((n>>4)&1)*4 + (n&3) within each 32-key group; the lane's
// own S^T registers then ARE the PV A-fragment (slot quad*8+j <-> key
// quad*4+16*(j>>2)+(j&3)). V^T is written sigma-permuted in gemm_qkv's
// epilogue (still 4-contiguous -> one ushort4 store per r-group).

typedef unsigned short u16;
typedef __attribute__((ext_vector_type(8))) short s16x8;   // 8 x bf16 MFMA frag
typedef __attribute__((ext_vector_type(4))) float f32x4;   // MFMA accum
typedef __attribute__((ext_vector_type(4))) unsigned short u16x4;

#define SEQ 1024
#define NHEAD 12
#define HD 64

__device__ __forceinline__ u16 f2bf(float f) {
  union { float f; uint32_t u; } v; v.f = f;
  uint32_t u = v.u;
  return (u16)((u + 0x7FFFu + ((u >> 16) & 1u)) >> 16);   // RNE
}

__device__ __forceinline__ float exp2_fast(float x) {
  return __builtin_amdgcn_exp2f(x);
}

__device__ __forceinline__ uint32_t pk_bf16(float a, float b) {
#if __has_builtin(__builtin_amdgcn_cvt_pk_bf16_f32)
  typedef __attribute__((ext_vector_type(2))) __bf16 bf2;
  union { bf2 v; uint32_t u; } c;
  c.v = __builtin_amdgcn_cvt_pk_bf16_f32(a, b);
  return c.u;
#else
  union { float f; uint32_t u; } ua, ub; ua.f = a; ub.f = b;
  const uint32_t ra = ua.u + 0x8000u, rb = ub.u + 0x8000u;
  return __builtin_amdgcn_perm(ra, rb, 0x03020706u);
#endif
}

__device__ __forceinline__ void gld_lds16(const void* g, void* l) {
  __builtin_amdgcn_global_load_lds((const __attribute__((address_space(1))) void*)g,
                                   (__attribute__((address_space(3))) void*)l, 16, 0, 0);
}

// One launch converts x, w_qkv, w_proj (3 disjoint fp32 sources -> contiguous
// bf16 workspace regions). Block-range select; branches are wave-uniform
// except at the two boundaries.
__global__ void cvt_bf16_3(const float* __restrict__ in0, u16* __restrict__ out0, int n0,
                           const float* __restrict__ in1, u16* __restrict__ out1, int n1,
                           const float* __restrict__ in2, u16* __restrict__ out2, int n2) {
  int i = blockIdx.x * blockDim.x + threadIdx.x;
  const float* in; u16* out;
  if (i < n0)            { in = in0; out = out0; }
  else if (i < n0 + n1)  { in = in1; out = out1; i -= n0; }
  else if (i < n0 + n1 + n2) { in = in2; out = out2; i -= n0 + n1; }
  else return;
  float4 f = ((const float4*)in)[i];
  u16x4 o;
  o.x = f2bf(f.x); o.y = f2bf(f.y); o.z = f2bf(f.z); o.w = f2bf(f.w);
  ((u16x4*)out)[i] = o;
}

// C = A[M,768] @ B^T, B row-major [N,768]. 128x128 tile, BK=64, 3 blocks/CU.
// EPI=0: scatter q(*0.125*log2e)/k to [B,H,N,64], V TRANSPOSED+sigma-permuted
//        to [B,H,64,N'] (N' = key-permuted column order for flash's in-reg P).
// EPI=1: +bias, fp32 out.
template <int EPI>
__global__ __launch_bounds__(256, 3)
void gemm_bt(const u16* __restrict__ A, const u16* __restrict__ B,
             u16* __restrict__ q, u16* __restrict__ k, u16* __restrict__ v,
             float* __restrict__ out, const float* __restrict__ bias) {
  __shared__ u16 As[128 * 64];
  __shared__ u16 Bs[128 * 64];
  const int tid = threadIdx.x;
  const int wv = tid >> 6, lane = tid & 63;
  const int quad = lane >> 4, l16 = lane & 15;
  const int m0 = blockIdx.x * 128, n0 = blockIdx.y * 128;
  const int wm = (wv & 1) * 64, wn = (wv >> 1) * 64;

  f32x4 acc[4][4];
#pragma unroll
  for (int i = 0; i < 4; i++)
#pragma unroll
    for (int j = 0; j < 4; j++) { acc[i][j].x = 0.f; acc[i][j].y = 0.f; acc[i][j].z = 0.f; acc[i][j].w = 0.f; }

  const int srow = (lane >> 3);
  const int scp = lane & 7;

  for (int kt = 0; kt < 768; kt += 64) {
    __syncthreads();
#pragma unroll
    for (int i = 0; i < 4; i++) {
      const int t = wv * 4 + i;
      const int row = t * 8 + srow;
      const int c = scp ^ (row & 7);
      gld_lds16(A + (size_t)(m0 + row) * 768 + kt + c * 8, &As[t * 512]);
      gld_lds16(B + (size_t)(n0 + row) * 768 + kt + c * 8, &Bs[t * 512]);
    }
    __syncthreads();
#pragma unroll
    for (int ks = 0; ks < 2; ks++) {
      s16x8 af[4], bf[4];
#pragma unroll
      for (int mi = 0; mi < 4; mi++) {
        const int ra = wm + mi * 16 + l16;
        const int ca = ((ks * 4 + quad) ^ (ra & 7)) * 8;
        af[mi] = *(const s16x8*)&As[ra * 64 + ca];
        const int rb = wn + mi * 16 + l16;
        const int cb = ((ks * 4 + quad) ^ (rb & 7)) * 8;
        bf[mi] = *(const s16x8*)&Bs[rb * 64 + cb];
      }
#pragma unroll
      for (int mi = 0; mi < 4; mi++)
#pragma unroll
        for (int ni = 0; ni < 4; ni++)
          acc[mi][ni] = __builtin_amdgcn_mfma_f32_16x16x32_bf16(af[mi], bf[ni], acc[mi][ni], 0, 0, 0);
    }
  }

  if (EPI == 0) {
#pragma unroll
    for (int ni = 0; ni < 4; ni++) {
      const int n = n0 + wn + ni * 16 + l16;
      const int which = n / 768;          // uniform per block (n-range within one third)
      const int rc = n % 768;
      const int head = rc >> 6, d = rc & 63;
      if (which == 2) {
        // V: transposed + sigma-permuted columns; r=0..3 stay contiguous -> 8B store
#pragma unroll
        for (int mi = 0; mi < 4; mi++) {
          const int mb = m0 + wm + mi * 16 + quad * 4;   // 4-aligned, same 1024-group for r=0..3
          const int b = mb >> 10, rrb = mb & 1023;
          const int vcol = (rrb & ~31) | (((rrb >> 2) & 3) << 3) | (((rrb >> 4) & 1) << 2);
          u16x4 pk4;
          pk4.x = f2bf(acc[mi][ni][0]); pk4.y = f2bf(acc[mi][ni][1]);
          pk4.z = f2bf(acc[mi][ni][2]); pk4.w = f2bf(acc[mi][ni][3]);
          *(u16x4*)&v[((size_t)(b * NHEAD + head) * HD + d) * SEQ + vcol] = pk4;
        }
      } else {
#pragma unroll
        for (int mi = 0; mi < 4; mi++) {
#pragma unroll
          for (int r = 0; r < 4; r++) {
            const int m = m0 + wm + mi * 16 + quad * 4 + r;
            const int b = m >> 10, rr = m & 1023;
            const float val = acc[mi][ni][r];
            if (which == 0)   // fold SCALE * log2(e) so flash uses 2^x directly
              q[((size_t)(b * NHEAD + head) * SEQ + rr) * HD + d] = f2bf(val * 0.18033688011112042f);
            else
              k[((size_t)(b * NHEAD + head) * SEQ + rr) * HD + d] = f2bf(val);
          }
        }
      }
    }
  } else {
#pragma unroll
    for (int mi = 0; mi < 4; mi++)
#pragma unroll
      for (int ni = 0; ni < 4; ni++)
#pragma unroll
        for (int r = 0; r < 4; r++) {
          const int m = m0 + wm + mi * 16 + quad * 4 + r;
          const int n = n0 + wn + ni * 16 + l16;
          out[(size_t)m * 768 + n] = acc[mi][ni][r] + bias[n];
        }
  }
}

// Flash attention, S^T form, no online max, 2^x, double-buffered K/V staging.
// P stays in registers: lane (q=l16, quad) holds S^T[key=t*16+quad*4+r][q];
// with sigma-permuted V^T, the packed s-regs ARE the PV A-fragment.
// l via MFMA-ones (key order irrelevant for the row sum).
__global__ __launch_bounds__(256, 3)
void flash_attn(const u16* __restrict__ Q, const u16* __restrict__ K,
                const u16* __restrict__ VT, u16* __restrict__ O) {
  __shared__ u16 Ks[2][64 * 64];        // [key][d], chunks swizzled by key&7
  __shared__ u16 Vs[2][64 * 64];        // [d][key'], chunks swizzled by d&7

  const int tid = threadIdx.x;
  const int wv = tid >> 6, lane = tid & 63;
  const int quad = lane >> 4, l16 = lane & 15;
  const int bh = blockIdx.x;
  const int q0 = blockIdx.y * 128 + wv * 32;
  const size_t base = (size_t)bh * SEQ * HD;
  const size_t vbase = (size_t)bh * HD * SEQ;

  const int sr0 = tid >> 3;
  const int sc0 = (tid & 7) ^ (sr0 & 7);
  const int sr1 = 32 + sr0;
  const int sc1 = (tid & 7) ^ (sr1 & 7);

  s16x8 qf[2][2];
#pragma unroll
  for (int g = 0; g < 2; g++)
#pragma unroll
    for (int ks = 0; ks < 2; ks++)
      qf[g][ks] = *(const s16x8*)(Q + base + (size_t)(q0 + g * 16 + l16) * HD + ks * 32 + quad * 8);

  const s16x8 ones = {0x3F80, 0x3F80, 0x3F80, 0x3F80, 0x3F80, 0x3F80, 0x3F80, 0x3F80};

  f32x4 acc[2][4], acc_l[2];
#pragma unroll
  for (int g = 0; g < 2; g++) {
    acc_l[g].x = 0.f; acc_l[g].y = 0.f; acc_l[g].z = 0.f; acc_l[g].w = 0.f;
#pragma unroll
    for (int t = 0; t < 4; t++) { acc[g][t].x = 0.f; acc[g][t].y = 0.f; acc[g][t].z = 0.f; acc[g][t].w = 0.f; }
  }

  const int swz = l16 & 7;

  gld_lds16(K + base + (size_t)sr0 * HD + sc0 * 8, &Ks[0][wv * 512]);
  gld_lds16(VT + vbase + (size_t)sr0 * SEQ + sc0 * 8, &Vs[0][wv * 512]);
  gld_lds16(K + base + (size_t)sr1 * HD + sc1 * 8, &Ks[0][2048 + wv * 512]);
  gld_lds16(VT + vbase + (size_t)sr1 * SEQ + sc1 * 8, &Vs[0][2048 + wv * 512]);

  for (int it = 0; it < 16; it++) {
    __syncthreads();
    if (it + 1 < 16) {
      const int n1 = (it + 1) * 64;
      const int nb = (it + 1) & 1;
      gld_lds16(K + base + (size_t)(n1 + sr0) * HD + sc0 * 8, &Ks[nb][wv * 512]);
      gld_lds16(VT + vbase + (size_t)sr0 * SEQ + n1 + sc0 * 8, &Vs[nb][wv * 512]);
      gld_lds16(K + base + (size_t)(n1 + sr1) * HD + sc1 * 8, &Ks[nb][2048 + wv * 512]);
      gld_lds16(VT + vbase + (size_t)sr1 * SEQ + n1 + sc1 * 8, &Vs[nb][2048 + wv * 512]);
    }
    const u16* __restrict__ ks = Ks[it & 1];
    const u16* __restrict__ vs = Vs[it & 1];

    // S^T = K Q^T (q pre-scaled by 0.125*log2e)
    f32x4 s0[4], s1[4];
    __builtin_amdgcn_s_setprio(1);
#pragma unroll
    for (int t = 0; t < 4; t++) {
      s0[t].x = 0.f; s0[t].y = 0.f; s0[t].z = 0.f; s0[t].w = 0.f;
      s1[t].x = 0.f; s1[t].y = 0.f; s1[t].z = 0.f; s1[t].w = 0.f;
      const u16* kr = &ks[(t * 16 + l16) * 64];
      const s16x8 kf0 = *(const s16x8*)&kr[(quad ^ swz) * 8];
      const s16x8 kf1 = *(const s16x8*)&kr[((4 + quad) ^ swz) * 8];
      s0[t] = __builtin_amdgcn_mfma_f32_16x16x32_bf16(kf0, qf[0][0], s0[t], 0, 0, 0);
      s0[t] = __builtin_amdgcn_mfma_f32_16x16x32_bf16(kf1, qf[0][1], s0[t], 0, 0, 0);
      s1[t] = __builtin_amdgcn_mfma_f32_16x16x32_bf16(kf0, qf[1][0], s1[t], 0, 0, 0);
      s1[t] = __builtin_amdgcn_mfma_f32_16x16x32_bf16(kf1, qf[1][1], s1[t], 0, 0, 0);
    }
    __builtin_amdgcn_s_setprio(0);

    // p = 2^s
#pragma unroll
    for (int t = 0; t < 4; t++)
#pragma unroll
      for (int r = 0; r < 4; r++) {
        s0[t][r] = exp2_fast(s0[t][r]);
        s1[t][r] = exp2_fast(s1[t][r]);
      }

    // O += P V ; l += P @ ones. A-frags built in-register: slot quad*8+j holds
    // key 32*ks2 + quad*4 + 16*(j>>2) + (j&3) = exactly s[2*ks2 + (j>>2)][j&3];
    // sigma-permuted Vs columns supply the matching keys.
    __builtin_amdgcn_s_setprio(1);
#pragma unroll
    for (int ks2 = 0; ks2 < 2; ks2++) {
      union { uint32_t w[4]; s16x8 v; } pa0, pa1;
      pa0.w[0] = pk_bf16(s0[2 * ks2][0], s0[2 * ks2][1]);
      pa0.w[1] = pk_bf16(s0[2 * ks2][2], s0[2 * ks2][3]);
      pa0.w[2] = pk_bf16(s0[2 * ks2 + 1][0], s0[2 * ks2 + 1][1]);
      pa0.w[3] = pk_bf16(s0[2 * ks2 + 1][2], s0[2 * ks2 + 1][3]);
      pa1.w[0] = pk_bf16(s1[2 * ks2][0], s1[2 * ks2][1]);
      pa1.w[1] = pk_bf16(s1[2 * ks2][2], s1[2 * ks2][3]);
      pa1.w[2] = pk_bf16(s1[2 * ks2 + 1][0], s1[2 * ks2 + 1][1]);
      pa1.w[3] = pk_bf16(s1[2 * ks2 + 1][2], s1[2 * ks2 + 1][3]);
      acc_l[0] = __builtin_amdgcn_mfma_f32_16x16x32_bf16(pa0.v, ones, acc_l[0], 0, 0, 0);
      acc_l[1] = __builtin_amdgcn_mfma_f32_16x16x32_bf16(pa1.v, ones, acc_l[1], 0, 0, 0);
      const int cp = ((ks2 * 4 + quad) ^ swz) * 8;
#pragma unroll
      for (int t2 = 0; t2 < 4; t2++) {
        const s16x8 vf = *(const s16x8*)&vs[(t2 * 16 + l16) * 64 + cp];
        acc[0][t2] = __builtin_amdgcn_mfma_f32_16x16x32_bf16(pa0.v, vf, acc[0][t2], 0, 0, 0);
        acc[1][t2] = __builtin_amdgcn_mfma_f32_16x16x32_bf16(pa1.v, vf, acc[1][t2], 0, 0, 0);
      }
    }
    __builtin_amdgcn_s_setprio(0);
  }

  // write attn_out bf16 [B, N, H*64]; acc_l rows coincide with acc rows
  const int b = bh / NHEAD, h = bh % NHEAD;
#pragma unroll
  for (int g = 0; g < 2; g++) {
#pragma unroll
    for (int r = 0; r < 4; r++) {
      const float li = 1.0f / acc_l[g][r];
      const int qrow = q0 + g * 16 + quad * 4 + r;
      u16* op = O + (size_t)(b * SEQ + qrow) * 768 + h * HD;
#pragma unroll
      for (int t2 = 0; t2 < 4; t2++)
        op[t2 * 16 + l16] = f2bf(acc[g][t2][r] * li);
    }
  }
}

extern "C" void kernel_launch(void* const* d_in, const int* in_sizes, int n_in,
                              void* d_out, int out_size, void* d_ws, size_t ws_size,
                              hipStream_t stream) {
  (void)in_sizes; (void)n_in; (void)out_size; (void)ws_size;
  const float* x      = (const float*)d_in[0];
  const float* w_qkv  = (const float*)d_in[1];
  const float* w_proj = (const float*)d_in[2];
  const float* b_proj = (const float*)d_in[3];

  const size_t SZ_X   = (size_t)16384 * 768;
  const size_t SZ_WQ  = (size_t)2304 * 768;
  const size_t SZ_WP  = (size_t)768 * 768;
  const size_t SZ_HED = (size_t)16 * NHEAD * SEQ * HD;

  u16* xb   = (u16*)d_ws;
  u16* wqb  = xb + SZ_X;
  u16* wpb  = wqb + SZ_WQ;
  u16* qb   = wpb + SZ_WP;
  u16* kb   = qb + SZ_HED;
  u16* vtb  = kb + SZ_HED;     // V transposed, sigma-permuted [bh][d][n']
  u16* attn = vtb + SZ_HED;

  const int n0 = (int)(SZ_X / 4), n1 = (int)(SZ_WQ / 4), n2 = (int)(SZ_WP / 4);
  const int nblk = (n0 + n1 + n2 + 255) / 256;
  cvt_bf16_3<<<nblk, 256, 0, stream>>>(x, xb, n0, w_qkv, wqb, n1, w_proj, wpb, n2);

  gemm_bt<0><<<dim3(128, 18), 256, 0, stream>>>(xb, wqb, qb, kb, vtb, nullptr, nullptr);
  flash_attn<<<dim3(192, 8), 256, 0, stream>>>(qb, kb, vtb, attn);
  gemm_bt<1><<<dim3(128, 6), 256, 0, stream>>>(attn, wpb, nullptr, nullptr, nullptr,
                                               (float*)d_out, b_proj);
}